// Round 7
// baseline (731.666 us; speedup 1.0000x reference)
//
#include <hip/hip_runtime.h>
#include <math.h>

// B=64, I=4096, C=32, D=d=16
#define ITILES 256
#define IPB    16    // i's per itile

// ---------------------------------------------------------------------------
// R7: bb=8 "full-batch" blocks. Grid = 256 blocks (1 per CU), 512 thr = 8
// waves; wave owns 8 batches b = wave*8..+7 -> block covers all 64 b.
// W is fetched from HBM exactly ONCE per pass.
// Lane: c = lane&31, D-half h = lane>>5 (D0 = 8h).
// W[i] (32 KB) double-buffered in LDS via async global_load_lds (width 16),
// TRANSPOSED on the gather side -> compute reads are stride-1 ds_read_b128
// with immediate offsets, 0 bank conflicts.
// x rides scalar loads (wave-uniform addresses) -> SGPR operands of v_fma.
//
// Rationale (R6 post-mortem): pass0==pass1 time and both pipes ~25% =>
// latency-bound, not throughput-bound. bb=8 gives each LDS wv 8 FMAs
// (per-wave-iter VALU ~2250 cyc) so compute covers gather/LDS/barrier
// latency. 1 block/CU => 8 waves/CU => 256-VGPR budget: u[64]+s_acc[64]
// working set fits without scratch spill.
// USE_V = 0: slab = sum_i u (uniform c folded into reduce scale), no u array.
// USE_V = 1: p = u.vg -> softmax over c (no max-sub; |p| bounded) ->
//            slab = sum_i c_ij*u.  8 independent chains interleave.
// ---------------------------------------------------------------------------
template<int USE_V>
__global__ __launch_bounds__(512, 2)
void pass_kernel(const float* __restrict__ Wg, const float* __restrict__ xg,
                 const float* __restrict__ vg, float* __restrict__ slab)
{
    __shared__ float4 lds_w[2][2048];   // 2 x 32 KB

    const int tid   = threadIdx.x;
    const int wave  = tid >> 6;
    const int lane  = tid & 63;
    const int c     = lane & 31;
    const int h     = lane >> 5;
    const int D0    = h * 8;
    const int itile = blockIdx.x;
    const int i0    = itile * IPB;
    const int b0    = wave * 8;
    const int b0u   = __builtin_amdgcn_readfirstlane(b0);

    const float4* W4 = (const float4*)Wg;
    const int gidx = c * 64 + 32 * h;   // gather base within W[i] (float4 units)

    // ---- prefetch W(i0) into buffer 0 (wave stages chunks m = 4*wave..4*wave+3)
    #pragma unroll
    for (int k = 0; k < 4; ++k) {
        const int m = wave * 4 + k;
        __builtin_amdgcn_global_load_lds(
            (const __attribute__((address_space(1))) void*)(W4 + (size_t)i0 * 2048 + gidx + m),
            (__attribute__((address_space(3))) void*)(&lds_w[0][m * 64]),
            16, 0, 0);
    }

    float s_acc[8][8];   // [j][bb]
    #pragma unroll
    for (int j = 0; j < 8; ++j)
        #pragma unroll
        for (int bb = 0; bb < 8; ++bb) s_acc[j][bb] = 0.f;

    const float* vgl = vg;   // redefined opaquely each iter: blocks LICM hoist

    for (int ii = 0; ii < IPB; ++ii) {
        const int i = i0 + ii;
        __syncthreads();   // buf[ii&1] staged; prior reads of buf[(ii+1)&1] done

        if (ii + 1 < IPB) {
            #pragma unroll
            for (int k = 0; k < 4; ++k) {
                const int m = wave * 4 + k;
                __builtin_amdgcn_global_load_lds(
                    (const __attribute__((address_space(1))) void*)(W4 + (size_t)(i + 1) * 2048 + gidx + m),
                    (__attribute__((address_space(3))) void*)(&lds_w[(ii + 1) & 1][m * 64]),
                    16, 0, 0);
            }
        }

        const float4* buf = lds_w[ii & 1];
        const float* xb = xg + (size_t)b0u * 65536 + (size_t)i * 16;

        if (USE_V == 0) {
            // ---- accumulate straight into s_acc (no u array)
            #pragma unroll
            for (int dblk = 0; dblk < 4; ++dblk) {
                float4 xs[8];   // wave-uniform -> scalar loads (SGPRs)
                #pragma unroll
                for (int bb = 0; bb < 8; ++bb)
                    xs[bb] = *(const float4*)(xb + (size_t)bb * 65536 + dblk * 4);
                #pragma unroll
                for (int j = 0; j < 8; ++j) {
                    float4 wv = buf[(4 * j + dblk) * 64 + lane];
                    #pragma unroll
                    for (int bb = 0; bb < 8; ++bb) {
                        s_acc[j][bb] = fmaf(wv.x, xs[bb].x, s_acc[j][bb]);
                        s_acc[j][bb] = fmaf(wv.y, xs[bb].y, s_acc[j][bb]);
                        s_acc[j][bb] = fmaf(wv.z, xs[bb].z, s_acc[j][bb]);
                        s_acc[j][bb] = fmaf(wv.w, xs[bb].w, s_acc[j][bb]);
                    }
                }
            }
        } else {
            // ---- u_hat: u[j][bb] = sum_d W[c, D0+j, d] * x[b0+bb, i, d]
            float u[8][8];
            #pragma unroll
            for (int j = 0; j < 8; ++j)
                #pragma unroll
                for (int bb = 0; bb < 8; ++bb) u[j][bb] = 0.f;

            #pragma unroll
            for (int dblk = 0; dblk < 4; ++dblk) {
                float4 xs[8];
                #pragma unroll
                for (int bb = 0; bb < 8; ++bb)
                    xs[bb] = *(const float4*)(xb + (size_t)bb * 65536 + dblk * 4);
                #pragma unroll
                for (int j = 0; j < 8; ++j) {
                    float4 wv = buf[(4 * j + dblk) * 64 + lane];
                    #pragma unroll
                    for (int bb = 0; bb < 8; ++bb) {
                        u[j][bb] = fmaf(wv.x, xs[bb].x, u[j][bb]);
                        u[j][bb] = fmaf(wv.y, xs[bb].y, u[j][bb]);
                        u[j][bb] = fmaf(wv.z, xs[bb].z, u[j][bb]);
                        u[j][bb] = fmaf(wv.w, xs[bb].w, u[j][bb]);
                    }
                }
            }

            // ---- v re-read (L2-hot, loop-invariant but NOT reg-hoisted)
            asm volatile("" : "+r"(vgl));
            // ---- routing: p -> softmax over c (no max-sub) -> s_acc += c_ij*u
            #pragma unroll
            for (int bb = 0; bb < 8; ++bb) {
                const float* vp = vgl + (size_t)(b0 + bb) * 512 + (size_t)(c * 16 + D0);
                const float4 va = *(const float4*)vp;
                const float4 vb = *(const float4*)(vp + 4);
                float p = 0.f;
                p = fmaf(u[0][bb], va.x, p); p = fmaf(u[1][bb], va.y, p);
                p = fmaf(u[2][bb], va.z, p); p = fmaf(u[3][bb], va.w, p);
                p = fmaf(u[4][bb], vb.x, p); p = fmaf(u[5][bb], vb.y, p);
                p = fmaf(u[6][bb], vb.z, p); p = fmaf(u[7][bb], vb.w, p);
                p += __shfl_xor(p, 32);   // combine D-halves (lanes l, l^32 share c)
                // |p| <= |u||v| ~ 12 -> exp safe without max subtraction
                float e = __expf(p);
                float t = e;
                t += __shfl_xor(t, 16);
                t += __shfl_xor(t, 8);
                t += __shfl_xor(t, 4);
                t += __shfl_xor(t, 2);
                t += __shfl_xor(t, 1);
                float cij = __fdividef(e, t);
                #pragma unroll
                for (int j = 0; j < 8; ++j)
                    s_acc[j][bb] = fmaf(cij, u[j][bb], s_acc[j][bb]);
            }
        }
    }

    // ---- write per-itile partial slab (contiguous per (itile,b))
    float4* slab4 = (float4*)slab;
    #pragma unroll
    for (int bb = 0; bb < 8; ++bb) {
        const int b = b0 + bb;
        size_t base = (size_t)itile * 8192 + (size_t)b * 128 + (size_t)(c * 4 + 2 * h);
        float4 lo = {s_acc[0][bb], s_acc[1][bb], s_acc[2][bb], s_acc[3][bb]};
        float4 hi = {s_acc[4][bb], s_acc[5][bb], s_acc[6][bb], s_acc[7][bb]};
        slab4[base]     = lo;
        slab4[base + 1] = hi;
    }
}

// ---------------------------------------------------------------------------
// Reduce 256 slabs -> s_j[b,c,D], squash -> out. If v1in != null, also emit
// vsum = out + v1in (pre-summed v12 for the next pass's u.(v1+v2) fold).
// ---------------------------------------------------------------------------
__global__ __launch_bounds__(256)
void reduce_squash(const float* __restrict__ slab, float* __restrict__ out, float scale,
                   const float* __restrict__ v1in, float* __restrict__ vsum)
{
    const int o = blockIdx.x * 256 + threadIdx.x;   // o = b*512 + c*16 + D
    float a[16];
    #pragma unroll
    for (int k = 0; k < 16; ++k) a[k] = 0.f;
    for (int g = 0; g < 16; ++g) {
        #pragma unroll
        for (int k = 0; k < 16; ++k)
            a[k] += slab[(size_t)(g * 16 + k) * 32768 + o];
    }
    float s = 0.f;
    #pragma unroll
    for (int k = 0; k < 16; ++k) s += a[k];
    s *= scale;
    float t = s * s;
    t += __shfl_xor(t, 1);
    t += __shfl_xor(t, 2);
    t += __shfl_xor(t, 4);
    t += __shfl_xor(t, 8);
    float r = s / (1.0f + t) / sqrtf(t + 1e-9f);
    out[o] = r;
    if (v1in) vsum[o] = r + v1in[o];
}

extern "C" void kernel_launch(void* const* d_in, const int* in_sizes, int n_in,
                              void* d_out, int out_size, void* d_ws, size_t ws_size,
                              hipStream_t stream)
{
    const float* x = (const float*)d_in[0];   // [64, 4096, 16]
    const float* W = (const float*)d_in[1];   // [1, 4096, 32, 16, 16]

    float* slab = (float*)d_ws;                     // 256 * 32768 floats = 32 MB
    float* v1   = slab + (size_t)ITILES * 32768;
    float* v2   = v1 + 32768;
    float* v12  = v2 + 32768;
    float* out  = (float*)d_out;

    // iter 1: uniform c (1/32 folded into reduce scale)
    hipLaunchKernelGGL((pass_kernel<0>), dim3(ITILES), dim3(512), 0, stream, W, x, (const float*)nullptr, slab);
    hipLaunchKernelGGL(reduce_squash,    dim3(128),    dim3(256), 0, stream, slab, v1, 1.0f / 32.0f, (const float*)nullptr, (float*)nullptr);
    // iter 2: p = u.v1 ; reduce also emits v12 = v1 + v2
    hipLaunchKernelGGL((pass_kernel<1>), dim3(ITILES), dim3(512), 0, stream, W, x, v1, slab);
    hipLaunchKernelGGL(reduce_squash,    dim3(128),    dim3(256), 0, stream, slab, v2, 1.0f, v1, v12);
    // iter 3: p = u.v1 + u.v2 = u.v12
    hipLaunchKernelGGL((pass_kernel<1>), dim3(ITILES), dim3(512), 0, stream, W, x, v12, slab);
    hipLaunchKernelGGL(reduce_squash,    dim3(128),    dim3(256), 0, stream, slab, out, 1.0f, (const float*)nullptr, (float*)nullptr);
}